// Round 16
// baseline (517.950 us; speedup 1.0000x reference)
//
#include <hip/hip_runtime.h>

using f32x4  = __attribute__((ext_vector_type(4))) float;
using short8 = __attribute__((ext_vector_type(8))) short;
using u32x4  = __attribute__((ext_vector_type(4))) unsigned int;
using ushort4v = __attribute__((ext_vector_type(4))) unsigned short;

#define DEV __device__ __forceinline__
#define MFMA16(a, b, c) __builtin_amdgcn_mfma_f32_16x16x32_bf16(a, b, c, 0, 0, 0)

// B=32, CIN=1, NBINS=128, NFRAMES=256, NFILT=64 -> Hc=64, Wc=128
// DDEC=512, G=1536, T=64, NCLS=17
// ctxW: [b][n][l] = [32][1536][64] f32
// Scan: 128 wgs = 4 batch-groups (8 b) x 32 j-slices (16 j).
// hbuf: [65][32][512] u32 (bf16 hi<<16|lo h)
// subflags: [65][4][32][2] int, padded x4 (16B apart); producer-wave granularity

DEV unsigned short f2bf(float f) {
  unsigned int u = __float_as_uint(f);
  unsigned int r = (u + 0x7fffu + ((u >> 16) & 1u)) >> 16;
  return (unsigned short)r;
}
DEV float bf2f(unsigned short s) { return __uint_as_float(((unsigned int)s) << 16); }
DEV float sigm(float x) { return 1.0f / (1.0f + expf(-x)); }

DEV void gload16(const void* g, void* l) {
  __builtin_amdgcn_global_load_lds(
      (const __attribute__((address_space(1))) void*)g,
      (__attribute__((address_space(3))) void*)l, 16, 0, 0);
}

// ---------------- K1: prep (split wih, float4-vectorized; zero ctxW) -------------
__global__ __launch_bounds__(256) void k_prep(
    const float* __restrict__ wih,
    unsigned short* __restrict__ wih_hi, unsigned short* __restrict__ wih_lo,
    float* __restrict__ ctxW) {
  unsigned int i4 = blockIdx.x * 256u + threadIdx.x;
  if (i4 < 3145728u) {  // 12582912 / 4
    f32x4 w = *(const f32x4*)&wih[i4 * 4];
    ushort4v hi, lo;
#pragma unroll
    for (int e = 0; e < 4; e++) {
      hi[e] = f2bf(w[e]);
      lo[e] = f2bf(w[e] - bf2f(hi[e]));
    }
    *(ushort4v*)&wih_hi[i4 * 4] = hi;
    *(ushort4v*)&wih_lo[i4 * 4] = lo;
  }
  if (i4 < 786432u) {  // 3145728 / 4 f32
    const f32x4 z4 = {0.f, 0.f, 0.f, 0.f};
    *(f32x4*)&ctxW[i4 * 4] = z4;
  }
}

// ---------------- K2: conv 3x3 stride2 pad1 -> context (bf16 hi/lo) --------------
__global__ __launch_bounds__(128) void k_conv(
    const float* __restrict__ x, const float* __restrict__ cw,
    unsigned short* __restrict__ ctx_hi, unsigned short* __restrict__ ctx_lo) {
  __shared__ float w[576];
  int t = threadIdx.x;
  for (int i = t; i < 576; i += 128) w[i] = cw[i];
  int blk = blockIdx.x;  // b*64 + h
  int b = blk >> 6, h = blk & 63;
  const float* xb = x + (size_t)b * 32768;
  int wcol = t;
  float xv[3][3];
  int ih0 = 2 * h - 1, iw0 = 2 * wcol - 1;
#pragma unroll
  for (int kh = 0; kh < 3; kh++) {
    int ih = ih0 + kh;
#pragma unroll
    for (int kw = 0; kw < 3; kw++) {
      int iw = iw0 + kw;
      bool ok = (ih >= 0) && (ih < 128) && (iw >= 0) && (iw < 256);
      xv[kh][kw] = ok ? xb[ih * 256 + iw] : 0.f;
    }
  }
  __syncthreads();
  size_t base = (size_t)blk * 8192 + wcol;
  for (int c = 0; c < 64; c++) {
    const float* wc = &w[c * 9];
    float acc = 0.f;
#pragma unroll
    for (int kh = 0; kh < 3; kh++)
#pragma unroll
      for (int kw = 0; kw < 3; kw++) acc += xv[kh][kw] * wc[kh * 3 + kw];
    unsigned short hi = f2bf(acc);
    ctx_hi[base + c * 128] = hi;
    ctx_lo[base + c * 128] = f2bf(acc - bf2f(hi));
  }
}

// ---------------- K3: ctxW += context @ W_ih^T  (split-bf16, split-K x4) ---------
// XCD-chunked bijective block remap (768 % 8 == 0).
__global__ __launch_bounds__(256) void k_gemm(
    const unsigned short* __restrict__ A_hi, const unsigned short* __restrict__ A_lo,
    const unsigned short* __restrict__ B_hi, const unsigned short* __restrict__ B_lo,
    float* __restrict__ ctxW, float* __restrict__ part, int use_part) {
  __shared__ unsigned short Ah[128 * 32], Al[128 * 32];
  __shared__ unsigned short Bh[128 * 32], Bl[128 * 32];  // 32 KB
  int tid = threadIdx.x;
  int wg = (blockIdx.x & 7) * 96 + (blockIdx.x >> 3);  // bijective
  int m0 = (wg & 15) * 128;
  int n0 = ((wg >> 4) % 12) * 128;
  int zb = wg / 192;
  size_t kb = (size_t)zb * 2048;
  int wave = tid >> 6, lane = tid & 63;
  int wm = wave >> 1, wn = wave & 1;
  const int srow = lane >> 2;
  const int sql = lane & 3;

  f32x4 acc[4][4];
  const f32x4 zero4 = {0.f, 0.f, 0.f, 0.f};
  for (int mi = 0; mi < 4; mi++)
    for (int ni = 0; ni < 4; ni++) acc[mi][ni] = zero4;

  for (int t = 0; t < 64; t++) {
    __syncthreads();
#pragma unroll
    for (int c = 0; c < 2; c++) {
      int seg = wave * 2 + c;
      int row = seg * 16 + srow;
      int scol = ((sql ^ ((row >> 1) & 3)) * 8);
      size_t ga = (size_t)(m0 + row) * 8192 + kb + t * 32 + scol;
      size_t gb = (size_t)(n0 + row) * 8192 + kb + t * 32 + scol;
      gload16(&A_hi[ga], &Ah[seg * 512]);
      gload16(&A_lo[ga], &Al[seg * 512]);
      gload16(&B_hi[gb], &Bh[seg * 512]);
      gload16(&B_lo[gb], &Bl[seg * 512]);
    }
    asm volatile("s_waitcnt vmcnt(0)" ::: "memory");
    __syncthreads();
    int q = lane >> 4;
    short8 ah[4], al4[4], bh[4], bl4[4];
#pragma unroll
    for (int mi = 0; mi < 4; mi++) {
      int r = wm * 64 + mi * 16 + (lane & 15);
      int kc = (q ^ ((r >> 1) & 3)) * 8;
      ah[mi]  = *(short8*)&Ah[r * 32 + kc];
      al4[mi] = *(short8*)&Al[r * 32 + kc];
    }
#pragma unroll
    for (int ni = 0; ni < 4; ni++) {
      int r = wn * 64 + ni * 16 + (lane & 15);
      int kc = (q ^ ((r >> 1) & 3)) * 8;
      bh[ni]  = *(short8*)&Bh[r * 32 + kc];
      bl4[ni] = *(short8*)&Bl[r * 32 + kc];
    }
#pragma unroll
    for (int mi = 0; mi < 4; mi++)
#pragma unroll
      for (int ni = 0; ni < 4; ni++) {
        acc[mi][ni] = MFMA16(ah[mi], bh[ni], acc[mi][ni]);
        acc[mi][ni] = MFMA16(ah[mi], bl4[ni], acc[mi][ni]);
        acc[mi][ni] = MFMA16(al4[mi], bh[ni], acc[mi][ni]);
      }
  }
  float* base = ctxW;
  if (use_part && zb > 0) base = part + (size_t)(zb - 1) * 3145728;
#pragma unroll
  for (int mi = 0; mi < 4; mi++)
#pragma unroll
    for (int ni = 0; ni < 4; ni++) {
      int n = n0 + wn * 64 + ni * 16 + (lane & 15);
      int mb = m0 + wm * 64 + mi * 16 + (lane >> 4) * 4;
      int bb = mb >> 6, l = mb & 63;
      size_t off = (size_t)(bb * 1536 + n) * 64 + l;
      if (use_part) {
        *(f32x4*)&base[off] = acc[mi][ni];
      } else {
#pragma unroll
        for (int r = 0; r < 4; r++) unsafeAtomicAdd(&ctxW[off + r], acc[mi][ni][r]);
      }
    }
}

// ---------------- K3r: reduce split-K partials into ctxW -------------------------
__global__ __launch_bounds__(256) void k_red(
    float* __restrict__ ctxW, const float* __restrict__ part) {
  unsigned int i4 = blockIdx.x * 256u + threadIdx.x;
  if (i4 >= 786432u) return;
  f32x4 s = *(const f32x4*)&ctxW[i4 * 4];
  s += *(const f32x4*)&part[i4 * 4];
  s += *(const f32x4*)&part[3145728 + i4 * 4];
  s += *(const f32x4*)&part[6291456 + i4 * 4];
  *(f32x4*)&ctxW[i4 * 4] = s;
}

// ---------------- K3b: init scan state -------------------------------------------
__global__ __launch_bounds__(256) void k_init(
    unsigned int* __restrict__ hbuf, int* __restrict__ flags) {
  int i = blockIdx.x * 256 + threadIdx.x;
  if (i < 16384) hbuf[i] = 0u;  // h0 = 0
  // subflags: [65][4][32][2] x4-padded = 66560 ints; t=0 slice (first 1024) set
  if (i < 66560) flags[i] = (i < 1024 && (i & 3) == 0) ? 1 : 0;
}

// ---------------- K4: scan — wave-5 overlapped poll, per-wave sub-flags ----------
__global__ __launch_bounds__(512) void k_scan(
    const float* __restrict__ ctxW, const float* __restrict__ whh,
    const float* __restrict__ kw, const float* __restrict__ bw,
    const float* __restrict__ ow, const float* __restrict__ ob,
    unsigned int* __restrict__ hbuf, int* __restrict__ flags,
    float* __restrict__ d_out) {
  __shared__ unsigned short whh_h[48 * 512], whh_l[48 * 512];  // swizzled
  __shared__ unsigned short h_h[9 * 512], h_l[9 * 512];        // row 8 = zeros
  __shared__ float ws_lds[8][68];   // padded
  __shared__ float gh_lds[16][52];  // padded
  __shared__ float gx1p[128][3];    // high-half gx partials (waves 3-4)
  __shared__ int   w0_l[8];
  __shared__ float obs[17];

  const int wg = blockIdx.x;
  const int g = wg & 31, bg = wg >> 5;
  const int j0 = g * 16;
  const int tid = threadIdx.x;
  const int wave = tid >> 6, lane = tid & 63;
  float h_prev = 0.f;         // owned (b,jj) for waves 6-7
  float gx0 = 0.f, gx1 = 0.f, gx2 = 0.f;
  float kappa = 0.f;          // wave w tracks kappa for b=w (replicated in lanes)

  // per-lane kw/bw slices in REGISTERS (loop-invariant; kills 16-way LDS conflict)
  const f32x4 kwr0 = *(const f32x4*)&kw[lane * 8];
  const f32x4 kwr1 = *(const f32x4*)&kw[lane * 8 + 4];
  const f32x4 bwr0 = *(const f32x4*)&bw[lane * 8];
  const f32x4 bwr1 = *(const f32x4*)&bw[lane * 8 + 4];

  // distributed out-projection: wg g -> batch g>>2, classes (g&3)*4.. (waves 0-1)
  const int f_bo  = g >> 2;
  const int f_ks0 = (g & 3) * 4;
  const int f_nk  = ((g & 3) == 3) ? 5 : 4;
  const bool f_act = tid < f_nk * 16;
  const int f_k  = f_ks0 + (tid >> 4);
  const int f_ln = tid & 15;
  const int f_sw = (f_bo & 7) << 4;

  if (tid < 17) obs[tid] = ob[tid];
  *(unsigned short*)((char*)h_h + 8 * 1024 + tid * 2) = 0;  // zero pad row
  *(unsigned short*)((char*)h_l + 8 * 1024 + tid * 2) = 0;
  // stage W_hh slice (48 rows x 512) -> LDS bf16 hi/lo, swizzled
#pragma unroll 4
  for (int r = 0; r < 48; r++) {
    int n_g = (r >> 4) * 512 + j0 + (r & 15);
    float w = whh[n_g * 512 + tid];
    unsigned short hi = f2bf(w);
    unsigned short lo = f2bf(w - bf2f(hi));
    int byte = (r * 1024 + tid * 2) ^ ((r & 7) << 4);
    *(unsigned short*)((char*)whh_h + byte) = hi;
    *(unsigned short*)((char*)whh_l + byte) = lo;
  }
  // pre-loop: confirm step-0 sub-flags (64 flags, one per lane of wave 5)
  if (wave == 5) {
    const int* fp = flags + (((0 * 4 + bg) * 32 + (lane >> 1)) * 2 + (lane & 1)) * 4;
    while (__hip_atomic_load(fp, __ATOMIC_RELAXED, __HIP_MEMORY_SCOPE_AGENT) == 0)
      __builtin_amdgcn_s_sleep(1);
  }
  __syncthreads();
  asm volatile("" ::: "memory");

  for (int t = 0; t < 64; t++) {
    // ---- Phase A/B: wave w owns b=w — stage h, kappa/beta (regs), weights ----
    {
      const unsigned int* src = hbuf + t * 16384 + (bg * 8 + wave) * 512 + lane * 8;
      u32x4 v0 = *(const u32x4*)(src);
      u32x4 v1 = *(const u32x4*)(src + 4);
      short8 hsv, lsv;
      float kd = 0.f, bd = 0.f;
#pragma unroll
      for (int e = 0; e < 8; e++) {
        unsigned int u = (e < 4) ? v0[e] : v1[e - 4];
        hsv[e] = (short)(u >> 16);
        lsv[e] = (short)(u & 0xffffu);
        float hv = __uint_as_float(u & 0xffff0000u) + __uint_as_float(u << 16);
        float kv = (e < 4) ? kwr0[e] : kwr1[e - 4];
        float bv = (e < 4) ? bwr0[e] : bwr1[e - 4];
        kd = fmaf(hv, kv, kd);
        bd = fmaf(hv, bv, bd);
      }
      int byte = (wave * 1024 + lane * 16) ^ ((wave & 7) << 4);
      *(short8*)((char*)h_h + byte) = hsv;
      *(short8*)((char*)h_l + byte) = lsv;
#pragma unroll
      for (int mm = 1; mm < 64; mm <<= 1) {   // full butterfly: result in ALL lanes
        kd += __shfl_xor(kd, mm, 64);
        bd += __shfl_xor(bd, mm, 64);
      }
      kappa += kd;
      float beta = expf(bd);
      float d = kappa - (float)lane;
      float wv = expf(-beta * d * d);
      ws_lds[wave][lane] = wv;
      if (g - 8 == wave)
        d_out[34816 + (((bg * 8 + wave) << 6) + t) * 64 + lane] = wv;
      if (lane == 0) {
        int w0 = ((int)roundf(kappa) - 14) & ~3;
        w0_l[wave] = w0 < 0 ? 0 : (w0 > 32 ? 32 : w0);
      }
    }
    __syncthreads();
    // ---- Phase C (waves 0-2): gh MFMA || D-high (waves 3-4) / D-low (6-7) ----
    if (wave < 3) {
      int nrow = wave * 16 + (lane & 15);
      int ar = lane & 15;
      int arow = ar < 8 ? ar : 8;  // rows 8-15 -> shared zero row
      int swb = (nrow & 7) << 4, swa = (arow & 7) << 4;
      f32x4 acc = {0.f, 0.f, 0.f, 0.f};
      for (int ks = 0; ks < 16; ks++) {
        int kb2 = ks * 64 + (lane >> 4) * 16;
        short8 ah = *(short8*)((char*)h_h + ((arow * 1024 + kb2) ^ swa));
        short8 al = *(short8*)((char*)h_l + ((arow * 1024 + kb2) ^ swa));
        short8 bh = *(short8*)((char*)whh_h + ((nrow * 1024 + kb2) ^ swb));
        short8 bl = *(short8*)((char*)whh_l + ((nrow * 1024 + kb2) ^ swb));
        acc = MFMA16(ah, bh, acc);
        acc = MFMA16(ah, bl, acc);
        acc = MFMA16(al, bh, acc);
      }
#pragma unroll
      for (int r = 0; r < 4; r++)
        gh_lds[(lane >> 4) * 4 + r][wave * 16 + (lane & 15)] = acc[r];
    } else if (wave == 3 || wave == 4) {
      int idx = tid - 192;          // 0..127
      int b = idx >> 4, jj = idx & 15;
      int w0 = w0_l[b];
      const float* cb =
          ctxW + (size_t)((bg * 8 + b) * 1536 + j0 + jj) * 64 + w0 + 16;
      float t0 = 0.f, t1 = 0.f, t2 = 0.f;
#pragma unroll
      for (int lc = 0; lc < 4; lc++) {
        f32x4 w4 = *(const f32x4*)&ws_lds[b][w0 + 16 + lc * 4];
        f32x4 c0 = *(const f32x4*)(cb + lc * 4);
        f32x4 c1 = *(const f32x4*)(cb + 32768 + lc * 4);
        f32x4 c2 = *(const f32x4*)(cb + 65536 + lc * 4);
#pragma unroll
        for (int qq = 0; qq < 4; qq++) {
          t0 = fmaf(w4[qq], c0[qq], t0);
          t1 = fmaf(w4[qq], c1[qq], t1);
          t2 = fmaf(w4[qq], c2[qq], t2);
        }
      }
      gx1p[idx][0] = t0;
      gx1p[idx][1] = t1;
      gx1p[idx][2] = t2;
    } else if (wave >= 6) {
      int idx = tid - 384;          // 0..127
      int b = idx >> 4, jj = idx & 15;
      int w0 = w0_l[b];
      const float* cb = ctxW + (size_t)((bg * 8 + b) * 1536 + j0 + jj) * 64 + w0;
      gx0 = gx1 = gx2 = 0.f;
#pragma unroll
      for (int lc = 0; lc < 4; lc++) {
        f32x4 w4 = *(const f32x4*)&ws_lds[b][w0 + lc * 4];
        f32x4 c0 = *(const f32x4*)(cb + lc * 4);
        f32x4 c1 = *(const f32x4*)(cb + 32768 + lc * 4);
        f32x4 c2 = *(const f32x4*)(cb + 65536 + lc * 4);
#pragma unroll
        for (int qq = 0; qq < 4; qq++) {
          gx0 = fmaf(w4[qq], c0[qq], gx0);
          gx1 = fmaf(w4[qq], c1[qq], gx1);
          gx2 = fmaf(w4[qq], c2[qq], gx2);
        }
      }
    }
    __syncthreads();
    // ---- Phase E (w6-7): gates + update + store h + vmcnt(0) + per-wave sub-flag
    // ---- Phase F (w0-1): out(t-1)   ||   wave 5: poll sub-flags for step t+1 ----
    if (wave >= 6) {
      int idx = tid - 384;
      int b = idx >> 4, jj = idx & 15;
      float rr = sigm(gx0 + gx1p[idx][0] + gh_lds[b][jj]);
      float zz = sigm(gx1 + gx1p[idx][1] + gh_lds[b][16 + jj]);
      float nn = tanhf(gx2 + gx1p[idx][2] + rr * gh_lds[b][32 + jj]);
      float h = (1.f - zz) * nn + zz * h_prev;
      h_prev = h;
      unsigned short hh = f2bf(h);
      unsigned short hl = f2bf(h - bf2f(hh));
      __hip_atomic_store(&hbuf[(t + 1) * 16384 + (bg * 8 + b) * 512 + j0 + jj],
                         ((unsigned int)hh << 16) | (unsigned int)hl,
                         __ATOMIC_RELAXED, __HIP_MEMORY_SCOPE_AGENT);
      asm volatile("s_waitcnt vmcnt(0)" ::: "memory");  // this wave's h drained
      if (lane == 0)
        __hip_atomic_store(
            &flags[((((t + 1) * 4 + bg) * 32 + g) * 2 + (wave - 6)) * 4], 1,
            __ATOMIC_RELAXED, __HIP_MEMORY_SCOPE_AGENT);
    } else if (wave == 5) {
      const int* fp =
          flags + ((((t + 1) * 4 + bg) * 32 + (lane >> 1)) * 2 + (lane & 1)) * 4;
      while (__hip_atomic_load(fp, __ATOMIC_RELAXED, __HIP_MEMORY_SCOPE_AGENT) == 0)
        __builtin_amdgcn_s_sleep(1);
    } else if (f_act && t > 0) {
      float s = 0.f;
#pragma unroll
      for (int c = 0; c < 4; c++) {
        int chunk = f_ln + c * 16;
        int byteoff = (f_bo * 1024 + chunk * 16) ^ f_sw;
        short8 hh8 = *(short8*)((char*)h_h + byteoff);
        short8 hl8 = *(short8*)((char*)h_l + byteoff);
        const float* owr = ow + f_k * 512 + chunk * 8;
#pragma unroll
        for (int e = 0; e < 8; e++) {
          float hv = bf2f((unsigned short)hh8[e]) + bf2f((unsigned short)hl8[e]);
          s = fmaf(hv, owr[e], s);
        }
      }
#pragma unroll
      for (int mm = 1; mm < 16; mm <<= 1) s += __shfl_xor(s, mm, 64);
      if (f_ln == 0)
        d_out[(((bg * 8 + f_bo) << 6) + (t - 1)) * 17 + f_k] = s + obs[f_k];
    }
    __syncthreads();  // step boundary: poll confirmed + h_lds free
    asm volatile("" ::: "memory");
  }
  // ---- final out(63) from hbuf[64] (flags t=64 confirmed by last poll) ----
  if (f_act) {
    const unsigned int* hrow =
        hbuf + 64 * 16384 + (bg * 8 + f_bo) * 512 + f_ln * 32;
    const float* owr = ow + f_k * 512 + f_ln * 32;
    float s = 0.f;
#pragma unroll
    for (int qq = 0; qq < 8; qq++) {
      u32x4 v = *(const u32x4*)(hrow + qq * 4);
      f32x4 w4 = *(const f32x4*)(owr + qq * 4);
#pragma unroll
      for (int e = 0; e < 4; e++) {
        float hv = __uint_as_float(v[e] & 0xffff0000u) +
                   __uint_as_float(v[e] << 16);
        s = fmaf(hv, w4[e], s);
      }
    }
#pragma unroll
    for (int mm = 1; mm < 16; mm <<= 1) s += __shfl_xor(s, mm, 64);
    if (f_ln == 0)
      d_out[(((bg * 8 + f_bo) << 6) + 63) * 17 + f_k] = s + obs[f_k];
  }
}

// ---------------- launch ----------------
extern "C" void kernel_launch(void* const* d_in, const int* in_sizes, int n_in,
                              void* d_out, int out_size, void* d_ws, size_t ws_size,
                              hipStream_t stream) {
  (void)in_sizes; (void)n_in; (void)out_size;
  const float* x   = (const float*)d_in[0];
  const float* cw  = (const float*)d_in[2];
  const float* kw  = (const float*)d_in[3];
  const float* bw  = (const float*)d_in[4];
  const float* wih = (const float*)d_in[5];
  const float* whh = (const float*)d_in[6];
  const float* ow  = (const float*)d_in[7];
  const float* ob  = (const float*)d_in[8];
  float* out = (float*)d_out;
  char* ws = (char*)d_ws;

  unsigned short* ctx_hi = (unsigned short*)(ws);
  unsigned short* ctx_lo = (unsigned short*)(ws + 33554432);
  unsigned short* wih_hi = (unsigned short*)(ws + 67108864);
  unsigned short* wih_lo = (unsigned short*)(ws + 92274688);
  float*          ctxW   = (float*)(ws + 120586240);       // [32][1536][64] f32
  // overlays (dead after k_gemm):
  unsigned int*   hbuf   = (unsigned int*)(ws + 67108864); // [65][16384] u32
  int*            flags  = (int*)(ws + 71368704);          // subflags, 266 KB
  // gated split-K partial buffers (3 x 12 MB at 128 MB):
  float*          part   = (float*)(ws + 134217728);
  int use_part = (ws_size >= 134217728ull + 3ull * 12582912ull) ? 1 : 0;

  k_prep<<<12288, 256, 0, stream>>>(wih, wih_hi, wih_lo, ctxW);
  k_conv<<<2048, 128, 0, stream>>>(x, cw, ctx_hi, ctx_lo);
  k_gemm<<<768, 256, 0, stream>>>(ctx_hi, ctx_lo, wih_hi, wih_lo,
                                  ctxW, part, use_part);
  if (use_part) k_red<<<3072, 256, 0, stream>>>(ctxW, part);
  k_init<<<520, 256, 0, stream>>>(hbuf, flags);
  k_scan<<<128, 512, 0, stream>>>(ctxW, whh, kw, bw, ow, ob, hbuf, flags, out);
}

// Round 17
// 405.446 us; speedup vs baseline: 1.2775x; 1.2775x over previous
//
#include <hip/hip_runtime.h>

using f32x4  = __attribute__((ext_vector_type(4))) float;
using short8 = __attribute__((ext_vector_type(8))) short;
using u32x4  = __attribute__((ext_vector_type(4))) unsigned int;
using ushort4v = __attribute__((ext_vector_type(4))) unsigned short;

#define DEV __device__ __forceinline__
#define MFMA16(a, b, c) __builtin_amdgcn_mfma_f32_16x16x32_bf16(a, b, c, 0, 0, 0)

// B=32, CIN=1, NBINS=128, NFRAMES=256, NFILT=64 -> Hc=64, Wc=128
// DDEC=512, G=1536, T=64, NCLS=17
// ctxW: [b][n][l] = [32][1536][64] f32
// Scan: 256 wgs = 8 batch-groups (4 b) x 32 j-slices (16 j).
// hbuf: [65][32][512] u32 (bf16 hi<<16|lo h); flags [65][8][32][16]

DEV unsigned short f2bf(float f) {
  unsigned int u = __float_as_uint(f);
  unsigned int r = (u + 0x7fffu + ((u >> 16) & 1u)) >> 16;
  return (unsigned short)r;
}
DEV float bf2f(unsigned short s) { return __uint_as_float(((unsigned int)s) << 16); }
DEV float sigm(float x) { return 1.0f / (1.0f + expf(-x)); }

DEV void gload16(const void* g, void* l) {
  __builtin_amdgcn_global_load_lds(
      (const __attribute__((address_space(1))) void*)g,
      (__attribute__((address_space(3))) void*)l, 16, 0, 0);
}

// ---------------- K1: prep (split wih, float4-vectorized; zero ctxW) -------------
__global__ __launch_bounds__(256) void k_prep(
    const float* __restrict__ wih,
    unsigned short* __restrict__ wih_hi, unsigned short* __restrict__ wih_lo,
    float* __restrict__ ctxW) {
  unsigned int i4 = blockIdx.x * 256u + threadIdx.x;
  if (i4 < 3145728u) {  // 12582912 / 4
    f32x4 w = *(const f32x4*)&wih[i4 * 4];
    ushort4v hi, lo;
#pragma unroll
    for (int e = 0; e < 4; e++) {
      hi[e] = f2bf(w[e]);
      lo[e] = f2bf(w[e] - bf2f(hi[e]));
    }
    *(ushort4v*)&wih_hi[i4 * 4] = hi;
    *(ushort4v*)&wih_lo[i4 * 4] = lo;
  }
  if (i4 < 786432u) {
    const f32x4 z4 = {0.f, 0.f, 0.f, 0.f};
    *(f32x4*)&ctxW[i4 * 4] = z4;
  }
}

// ---------------- K2: conv 3x3 stride2 pad1 -> context (bf16 hi/lo) --------------
__global__ __launch_bounds__(128) void k_conv(
    const float* __restrict__ x, const float* __restrict__ cw,
    unsigned short* __restrict__ ctx_hi, unsigned short* __restrict__ ctx_lo) {
  __shared__ float w[576];
  int t = threadIdx.x;
  for (int i = t; i < 576; i += 128) w[i] = cw[i];
  int blk = blockIdx.x;  // b*64 + h
  int b = blk >> 6, h = blk & 63;
  const float* xb = x + (size_t)b * 32768;
  int wcol = t;
  float xv[3][3];
  int ih0 = 2 * h - 1, iw0 = 2 * wcol - 1;
#pragma unroll
  for (int kh = 0; kh < 3; kh++) {
    int ih = ih0 + kh;
#pragma unroll
    for (int kw = 0; kw < 3; kw++) {
      int iw = iw0 + kw;
      bool ok = (ih >= 0) && (ih < 128) && (iw >= 0) && (iw < 256);
      xv[kh][kw] = ok ? xb[ih * 256 + iw] : 0.f;
    }
  }
  __syncthreads();
  size_t base = (size_t)blk * 8192 + wcol;
  for (int c = 0; c < 64; c++) {
    const float* wc = &w[c * 9];
    float acc = 0.f;
#pragma unroll
    for (int kh = 0; kh < 3; kh++)
#pragma unroll
      for (int kw = 0; kw < 3; kw++) acc += xv[kh][kw] * wc[kh * 3 + kw];
    unsigned short hi = f2bf(acc);
    ctx_hi[base + c * 128] = hi;
    ctx_lo[base + c * 128] = f2bf(acc - bf2f(hi));
  }
}

// ---------------- K3: ctxW += context @ W_ih^T  (split-bf16, split-K x4) ---------
// XCD-chunked bijective block remap (768 % 8 == 0).
__global__ __launch_bounds__(256) void k_gemm(
    const unsigned short* __restrict__ A_hi, const unsigned short* __restrict__ A_lo,
    const unsigned short* __restrict__ B_hi, const unsigned short* __restrict__ B_lo,
    float* __restrict__ ctxW, float* __restrict__ part, int use_part) {
  __shared__ unsigned short Ah[128 * 32], Al[128 * 32];
  __shared__ unsigned short Bh[128 * 32], Bl[128 * 32];  // 32 KB
  int tid = threadIdx.x;
  int wg = (blockIdx.x & 7) * 96 + (blockIdx.x >> 3);  // bijective
  int m0 = (wg & 15) * 128;
  int n0 = ((wg >> 4) % 12) * 128;
  int zb = wg / 192;
  size_t kb = (size_t)zb * 2048;
  int wave = tid >> 6, lane = tid & 63;
  int wm = wave >> 1, wn = wave & 1;
  const int srow = lane >> 2;
  const int sql = lane & 3;

  f32x4 acc[4][4];
  const f32x4 zero4 = {0.f, 0.f, 0.f, 0.f};
  for (int mi = 0; mi < 4; mi++)
    for (int ni = 0; ni < 4; ni++) acc[mi][ni] = zero4;

  for (int t = 0; t < 64; t++) {
    __syncthreads();
#pragma unroll
    for (int c = 0; c < 2; c++) {
      int seg = wave * 2 + c;
      int row = seg * 16 + srow;
      int scol = ((sql ^ ((row >> 1) & 3)) * 8);
      size_t ga = (size_t)(m0 + row) * 8192 + kb + t * 32 + scol;
      size_t gb = (size_t)(n0 + row) * 8192 + kb + t * 32 + scol;
      gload16(&A_hi[ga], &Ah[seg * 512]);
      gload16(&A_lo[ga], &Al[seg * 512]);
      gload16(&B_hi[gb], &Bh[seg * 512]);
      gload16(&B_lo[gb], &Bl[seg * 512]);
    }
    asm volatile("s_waitcnt vmcnt(0)" ::: "memory");
    __syncthreads();
    int q = lane >> 4;
    short8 ah[4], al4[4], bh[4], bl4[4];
#pragma unroll
    for (int mi = 0; mi < 4; mi++) {
      int r = wm * 64 + mi * 16 + (lane & 15);
      int kc = (q ^ ((r >> 1) & 3)) * 8;
      ah[mi]  = *(short8*)&Ah[r * 32 + kc];
      al4[mi] = *(short8*)&Al[r * 32 + kc];
    }
#pragma unroll
    for (int ni = 0; ni < 4; ni++) {
      int r = wn * 64 + ni * 16 + (lane & 15);
      int kc = (q ^ ((r >> 1) & 3)) * 8;
      bh[ni]  = *(short8*)&Bh[r * 32 + kc];
      bl4[ni] = *(short8*)&Bl[r * 32 + kc];
    }
#pragma unroll
    for (int mi = 0; mi < 4; mi++)
#pragma unroll
      for (int ni = 0; ni < 4; ni++) {
        acc[mi][ni] = MFMA16(ah[mi], bh[ni], acc[mi][ni]);
        acc[mi][ni] = MFMA16(ah[mi], bl4[ni], acc[mi][ni]);
        acc[mi][ni] = MFMA16(al4[mi], bh[ni], acc[mi][ni]);
      }
  }
  float* base = ctxW;
  if (use_part && zb > 0) base = part + (size_t)(zb - 1) * 3145728;
#pragma unroll
  for (int mi = 0; mi < 4; mi++)
#pragma unroll
    for (int ni = 0; ni < 4; ni++) {
      int n = n0 + wn * 64 + ni * 16 + (lane & 15);
      int mb = m0 + wm * 64 + mi * 16 + (lane >> 4) * 4;
      int bb = mb >> 6, l = mb & 63;
      size_t off = (size_t)(bb * 1536 + n) * 64 + l;
      if (use_part) {
        *(f32x4*)&base[off] = acc[mi][ni];
      } else {
#pragma unroll
        for (int r = 0; r < 4; r++) unsafeAtomicAdd(&ctxW[off + r], acc[mi][ni][r]);
      }
    }
}

// ---------------- K3r: reduce split-K partials into ctxW -------------------------
__global__ __launch_bounds__(256) void k_red(
    float* __restrict__ ctxW, const float* __restrict__ part) {
  unsigned int i4 = blockIdx.x * 256u + threadIdx.x;
  if (i4 >= 786432u) return;
  f32x4 s = *(const f32x4*)&ctxW[i4 * 4];
  s += *(const f32x4*)&part[i4 * 4];
  s += *(const f32x4*)&part[3145728 + i4 * 4];
  s += *(const f32x4*)&part[6291456 + i4 * 4];
  *(f32x4*)&ctxW[i4 * 4] = s;
}

// ---------------- K3b: init scan state -------------------------------------------
__global__ __launch_bounds__(256) void k_init(
    unsigned int* __restrict__ hbuf, int* __restrict__ flags) {
  int i = blockIdx.x * 256 + threadIdx.x;
  if (i < 16384) hbuf[i] = 0u;  // h0 = 0
  // flags [65][8][32][16]: 266240 ints; t=0 slice = first 4096, every 16th set
  if (i < 266240) flags[i] = (i < 4096 && (i & 15) == 0) ? 1 : 0;
}

// ---------------- K4: scan — 256 wgs (8 bg x 4 b x 32 j), R15 sync ---------------
__global__ __launch_bounds__(512) void k_scan(
    const float* __restrict__ ctxW, const float* __restrict__ whh,
    const float* __restrict__ kw, const float* __restrict__ bw,
    const float* __restrict__ ow, const float* __restrict__ ob,
    unsigned int* __restrict__ hbuf, int* __restrict__ flags,
    float* __restrict__ d_out) {
  __shared__ unsigned short whh_h[48 * 512], whh_l[48 * 512];  // swizzled
  __shared__ unsigned short h_h[5 * 512], h_l[5 * 512];        // rows 0-3; row 4 = 0
  __shared__ float ws_lds[4][68];   // padded
  __shared__ float gh_lds[16][52];  // padded (rows 4-15 receive zeros)
  __shared__ int   w0_l[4];
  __shared__ float obs[17];

  const int wg = blockIdx.x;
  const int g = wg & 31, bg = wg >> 5;
  const int j0 = g * 16;
  const int tid = threadIdx.x;
  const int wave = tid >> 6, lane = tid & 63;
  float h_prev = 0.f;         // owned (b,jj) for waves 6-7 half==0
  float kappa = 0.f;          // waves 0-3: kappa for b = bg*4 + wave

  // per-lane kw/bw slices in registers (used by waves 0-3)
  const f32x4 kwr0 = *(const f32x4*)&kw[lane * 8];
  const f32x4 kwr1 = *(const f32x4*)&kw[lane * 8 + 4];
  const f32x4 bwr0 = *(const f32x4*)&bw[lane * 8];
  const f32x4 bwr1 = *(const f32x4*)&bw[lane * 8 + 4];

  // Phase-D mapping (waves 6-7): 2 threads per (b,jj), half-window each
  const int d_idx  = tid - 384;
  const int d_half = d_idx & 1;
  const int d_b    = (d_idx >> 1) >> 4;
  const int d_jj   = (d_idx >> 1) & 15;

  // Phase-F mapping (waves 3-4): wg g -> batch g>>3, classes (g&7)*2..
  const int f_bo  = g >> 3;                    // local batch 0..3
  const int f_ks0 = (g & 7) * 2;
  const int f_nk  = ((g & 7) == 7) ? 3 : 2;    // 17 = 7*2 + 3
  const int f_t   = tid - 192;                 // waves 3-4: 0..127
  const bool f_act = (f_t >= 0) && (f_t < f_nk * 16);
  const int f_k  = f_ks0 + (f_t >> 4);
  const int f_ln = f_t & 15;
  const int f_sw = f_bo << 4;

  if (tid < 17) obs[tid] = ob[tid];
  *(unsigned short*)((char*)h_h + 4 * 1024 + tid * 2) = 0;  // zero pad row 4
  *(unsigned short*)((char*)h_l + 4 * 1024 + tid * 2) = 0;
  // stage W_hh slice (48 rows x 512) -> LDS bf16 hi/lo, swizzled
#pragma unroll 4
  for (int r = 0; r < 48; r++) {
    int n_g = (r >> 4) * 512 + j0 + (r & 15);
    float w = whh[n_g * 512 + tid];
    unsigned short hi = f2bf(w);
    unsigned short lo = f2bf(w - bf2f(hi));
    int byte = (r * 1024 + tid * 2) ^ ((r & 7) << 4);
    *(unsigned short*)((char*)whh_h + byte) = hi;
    *(unsigned short*)((char*)whh_l + byte) = lo;
  }
  __syncthreads();

  for (int t = 0; t < 64; t++) {
    // ---- poll: all 32 wgs of this batch-group published step t ----
    if (tid < 32) {
      const int* fp = flags + ((t * 8 + bg) * 32 + tid) * 16;
      while (__hip_atomic_load(fp, __ATOMIC_RELAXED, __HIP_MEMORY_SCOPE_AGENT) == 0)
        __builtin_amdgcn_s_sleep(1);
    }
    __syncthreads();
    asm volatile("" ::: "memory");
    // ---- Phase A (waves 0-3): stage h row b=wave, kappa/beta (regs), weights ----
    if (wave < 4) {
      const unsigned int* src =
          hbuf + t * 16384 + (bg * 4 + wave) * 512 + lane * 8;
      u32x4 v0 = *(const u32x4*)(src);
      u32x4 v1 = *(const u32x4*)(src + 4);
      short8 hsv, lsv;
      float kd = 0.f, bd = 0.f;
#pragma unroll
      for (int e = 0; e < 8; e++) {
        unsigned int u = (e < 4) ? v0[e] : v1[e - 4];
        hsv[e] = (short)(u >> 16);
        lsv[e] = (short)(u & 0xffffu);
        float hv = __uint_as_float(u & 0xffff0000u) + __uint_as_float(u << 16);
        float kv = (e < 4) ? kwr0[e] : kwr1[e - 4];
        float bv = (e < 4) ? bwr0[e] : bwr1[e - 4];
        kd = fmaf(hv, kv, kd);
        bd = fmaf(hv, bv, bd);
      }
      int byte = (wave * 1024 + lane * 16) ^ (wave << 4);
      *(short8*)((char*)h_h + byte) = hsv;
      *(short8*)((char*)h_l + byte) = lsv;
#pragma unroll
      for (int mm = 1; mm < 64; mm <<= 1) {
        kd += __shfl_xor(kd, mm, 64);
        bd += __shfl_xor(bd, mm, 64);
      }
      kappa += kd;
      float beta = expf(bd);
      float d = kappa - (float)lane;
      float wv = expf(-beta * d * d);
      ws_lds[wave][lane] = wv;
      if (g - 8 == wave)
        d_out[34816 + (((bg * 4 + wave) << 6) + t) * 64 + lane] = wv;
      if (lane == 0) {
        int w0 = ((int)roundf(kappa) - 14) & ~3;
        w0_l[wave] = w0 < 0 ? 0 : (w0 > 32 ? 32 : w0);
      }
    }
    __syncthreads();
    // ---- Phase C (waves 0-2): gh MFMA || D (waves 6-7, half-window) ||
    // ---- Phase F (waves 3-4): out(t-1) ----
    if (wave < 3) {
      int nrow = wave * 16 + (lane & 15);
      int ar = lane & 15;
      int arow = ar < 4 ? ar : 4;  // rows 4-15 -> shared zero row
      int swb = (nrow & 7) << 4, swa = arow << 4;
      f32x4 acc = {0.f, 0.f, 0.f, 0.f};
      for (int ks = 0; ks < 16; ks++) {
        int kb2 = ks * 64 + (lane >> 4) * 16;
        short8 ah = *(short8*)((char*)h_h + ((arow * 1024 + kb2) ^ swa));
        short8 al = *(short8*)((char*)h_l + ((arow * 1024 + kb2) ^ swa));
        short8 bh = *(short8*)((char*)whh_h + ((nrow * 1024 + kb2) ^ swb));
        short8 bl = *(short8*)((char*)whh_l + ((nrow * 1024 + kb2) ^ swb));
        acc = MFMA16(ah, bh, acc);
        acc = MFMA16(ah, bl, acc);
        acc = MFMA16(al, bh, acc);
      }
#pragma unroll
      for (int r = 0; r < 4; r++)
        gh_lds[(lane >> 4) * 4 + r][wave * 16 + (lane & 15)] = acc[r];
    } else if (f_act && t > 0) {
      float s = 0.f;
#pragma unroll
      for (int c = 0; c < 4; c++) {
        int chunk = f_ln + c * 16;
        int byteoff = (f_bo * 1024 + chunk * 16) ^ f_sw;
        short8 hh8 = *(short8*)((char*)h_h + byteoff);
        short8 hl8 = *(short8*)((char*)h_l + byteoff);
        const float* owr = ow + f_k * 512 + chunk * 8;
#pragma unroll
        for (int e = 0; e < 8; e++) {
          float hv = bf2f((unsigned short)hh8[e]) + bf2f((unsigned short)hl8[e]);
          s = fmaf(hv, owr[e], s);
        }
      }
#pragma unroll
      for (int mm = 1; mm < 16; mm <<= 1) s += __shfl_xor(s, mm, 64);
      if (f_ln == 0)
        d_out[(((bg * 4 + f_bo) << 6) + (t - 1)) * 17 + f_k] = s + obs[f_k];
    }
    float gx0 = 0.f, gx1 = 0.f, gx2 = 0.f;
    if (wave >= 6) {
      int w0 = w0_l[d_b];
      const float* cb = ctxW +
          (size_t)((bg * 4 + d_b) * 1536 + j0 + d_jj) * 64 + w0 + d_half * 16;
#pragma unroll
      for (int lc = 0; lc < 4; lc++) {
        f32x4 w4 = *(const f32x4*)&ws_lds[d_b][w0 + d_half * 16 + lc * 4];
        f32x4 c0 = *(const f32x4*)(cb + lc * 4);
        f32x4 c1 = *(const f32x4*)(cb + 32768 + lc * 4);
        f32x4 c2 = *(const f32x4*)(cb + 65536 + lc * 4);
#pragma unroll
        for (int qq = 0; qq < 4; qq++) {
          gx0 = fmaf(w4[qq], c0[qq], gx0);
          gx1 = fmaf(w4[qq], c1[qq], gx1);
          gx2 = fmaf(w4[qq], c2[qq], gx2);
        }
      }
      // combine halves: half0 holds low sum, half1 high sum; pair lanes differ by 1
      float o0 = __shfl_xor(gx0, 1, 64);
      float o1 = __shfl_xor(gx1, 1, 64);
      float o2 = __shfl_xor(gx2, 1, 64);
      if (d_half == 0) { gx0 += o0; gx1 += o1; gx2 += o2; }
      else             { gx0 = o0 + gx0; gx1 = o1 + gx1; gx2 = o2 + gx2; }
    }
    __syncthreads();
    // ---- Phase E (waves 6-7, half==0): gates + update + publish h ----
    if (wave >= 6 && d_half == 0) {
      float rr = sigm(gx0 + gh_lds[d_b][d_jj]);
      float zz = sigm(gx1 + gh_lds[d_b][16 + d_jj]);
      float nn = tanhf(gx2 + rr * gh_lds[d_b][32 + d_jj]);
      float h = (1.f - zz) * nn + zz * h_prev;
      h_prev = h;
      unsigned short hh = f2bf(h);
      unsigned short hl = f2bf(h - bf2f(hh));
      __hip_atomic_store(&hbuf[(t + 1) * 16384 + (bg * 4 + d_b) * 512 + j0 + d_jj],
                         ((unsigned int)hh << 16) | (unsigned int)hl,
                         __ATOMIC_RELAXED, __HIP_MEMORY_SCOPE_AGENT);
    }
    __syncthreads();  // drain h stores
    if (tid == 0)
      __hip_atomic_store(&flags[(((t + 1) * 8 + bg) * 32 + g) * 16], 1,
                         __ATOMIC_RELAXED, __HIP_MEMORY_SCOPE_AGENT);
  }
  // ---- final out(63) from hbuf[64] ----
  if (tid < 32) {
    const int* fp = flags + ((64 * 8 + bg) * 32 + tid) * 16;
    while (__hip_atomic_load(fp, __ATOMIC_RELAXED, __HIP_MEMORY_SCOPE_AGENT) == 0)
      __builtin_amdgcn_s_sleep(1);
  }
  __syncthreads();
  asm volatile("" ::: "memory");
  if (f_act) {
    const unsigned int* hrow =
        hbuf + 64 * 16384 + (bg * 4 + f_bo) * 512 + f_ln * 32;
    const float* owr = ow + f_k * 512 + f_ln * 32;
    float s = 0.f;
#pragma unroll
    for (int qq = 0; qq < 8; qq++) {
      u32x4 v = *(const u32x4*)(hrow + qq * 4);
      f32x4 w4 = *(const f32x4*)(owr + qq * 4);
#pragma unroll
      for (int e = 0; e < 4; e++) {
        float hv = __uint_as_float(v[e] & 0xffff0000u) +
                   __uint_as_float(v[e] << 16);
        s = fmaf(hv, w4[e], s);
      }
    }
#pragma unroll
    for (int mm = 1; mm < 16; mm <<= 1) s += __shfl_xor(s, mm, 64);
    if (f_ln == 0)
      d_out[(((bg * 4 + f_bo) << 6) + 63) * 17 + f_k] = s + obs[f_k];
  }
}

// ---------------- launch ----------------
extern "C" void kernel_launch(void* const* d_in, const int* in_sizes, int n_in,
                              void* d_out, int out_size, void* d_ws, size_t ws_size,
                              hipStream_t stream) {
  (void)in_sizes; (void)n_in; (void)out_size;
  const float* x   = (const float*)d_in[0];
  const float* cw  = (const float*)d_in[2];
  const float* kw  = (const float*)d_in[3];
  const float* bw  = (const float*)d_in[4];
  const float* wih = (const float*)d_in[5];
  const float* whh = (const float*)d_in[6];
  const float* ow  = (const float*)d_in[7];
  const float* ob  = (const float*)d_in[8];
  float* out = (float*)d_out;
  char* ws = (char*)d_ws;

  unsigned short* ctx_hi = (unsigned short*)(ws);
  unsigned short* ctx_lo = (unsigned short*)(ws + 33554432);
  unsigned short* wih_hi = (unsigned short*)(ws + 67108864);
  unsigned short* wih_lo = (unsigned short*)(ws + 92274688);
  float*          ctxW   = (float*)(ws + 120586240);       // [32][1536][64] f32
  // overlays (dead after k_gemm):
  unsigned int*   hbuf   = (unsigned int*)(ws + 67108864); // [65][16384] u32
  int*            flags  = (int*)(ws + 71368704);          // [65][8][32][16] = 1 MB
  // gated split-K partial buffers (3 x 12 MB at 128 MB):
  float*          part   = (float*)(ws + 134217728);
  int use_part = (ws_size >= 134217728ull + 3ull * 12582912ull) ? 1 : 0;

  k_prep<<<12288, 256, 0, stream>>>(wih, wih_hi, wih_lo, ctxW);
  k_conv<<<2048, 128, 0, stream>>>(x, cw, ctx_hi, ctx_lo);
  k_gemm<<<768, 256, 0, stream>>>(ctx_hi, ctx_lo, wih_hi, wih_lo,
                                  ctxW, part, use_part);
  if (use_part) k_red<<<3072, 256, 0, stream>>>(ctxW, part);
  k_init<<<1040, 256, 0, stream>>>(hbuf, flags);
  k_scan<<<256, 512, 0, stream>>>(ctxW, whh, kw, bw, ow, ob, hbuf, flags, out);
}

// Round 18
// 357.279 us; speedup vs baseline: 1.4497x; 1.1348x over previous
//
#include <hip/hip_runtime.h>

using f32x4  = __attribute__((ext_vector_type(4))) float;
using short8 = __attribute__((ext_vector_type(8))) short;
using u32x4  = __attribute__((ext_vector_type(4))) unsigned int;
using ushort4v = __attribute__((ext_vector_type(4))) unsigned short;

#define DEV __device__ __forceinline__
#define MFMA16(a, b, c) __builtin_amdgcn_mfma_f32_16x16x32_bf16(a, b, c, 0, 0, 0)

// B=32, CIN=1, NBINS=128, NFRAMES=256, NFILT=64 -> Hc=64, Wc=128
// DDEC=512, G=1536, T=64, NCLS=17
// ctxW: [b][n][l] = [32][1536][64] f32
// GEMM: 2-term split — exact A (ctx hi+lo) x rounded-bf16 B (wih_r).
// Scan: 256 wgs = 8 batch-groups (4 b) x 32 j-slices (16 j). (R17 structure)
// hbuf: [65][32][512] u32; flags [65][8][32][16] — in old wih_lo region.

DEV unsigned short f2bf(float f) {
  unsigned int u = __float_as_uint(f);
  unsigned int r = (u + 0x7fffu + ((u >> 16) & 1u)) >> 16;
  return (unsigned short)r;
}
DEV float bf2f(unsigned short s) { return __uint_as_float(((unsigned int)s) << 16); }
DEV float sigm(float x) { return 1.0f / (1.0f + expf(-x)); }

DEV void gload16(const void* g, void* l) {
  __builtin_amdgcn_global_load_lds(
      (const __attribute__((address_space(1))) void*)g,
      (__attribute__((address_space(3))) void*)l, 16, 0, 0);
}

// ---------------- K1: prep (round wih -> bf16; zero ctxW; init scan state) -------
__global__ __launch_bounds__(256) void k_prep(
    const float* __restrict__ wih, unsigned short* __restrict__ wih_r,
    float* __restrict__ ctxW, unsigned int* __restrict__ hbuf,
    int* __restrict__ flags) {
  unsigned int i4 = blockIdx.x * 256u + threadIdx.x;
  if (i4 < 3145728u) {  // 12582912 / 4
    f32x4 w = *(const f32x4*)&wih[i4 * 4];
    ushort4v r;
#pragma unroll
    for (int e = 0; e < 4; e++) r[e] = f2bf(w[e]);
    *(ushort4v*)&wih_r[i4 * 4] = r;
  }
  if (i4 < 786432u) {
    const f32x4 z4 = {0.f, 0.f, 0.f, 0.f};
    *(f32x4*)&ctxW[i4 * 4] = z4;
  }
  if (i4 < 16384u) hbuf[i4] = 0u;  // h0 = 0
  if (i4 < 266240u) flags[i4] = (i4 < 4096u && (i4 & 15u) == 0u) ? 1 : 0;
}

// ---------------- K2: conv 3x3 stride2 pad1 -> context (bf16 hi/lo) --------------
__global__ __launch_bounds__(128) void k_conv(
    const float* __restrict__ x, const float* __restrict__ cw,
    unsigned short* __restrict__ ctx_hi, unsigned short* __restrict__ ctx_lo) {
  __shared__ float w[576];
  int t = threadIdx.x;
  for (int i = t; i < 576; i += 128) w[i] = cw[i];
  int blk = blockIdx.x;  // b*64 + h
  int b = blk >> 6, h = blk & 63;
  const float* xb = x + (size_t)b * 32768;
  int wcol = t;
  float xv[3][3];
  int ih0 = 2 * h - 1, iw0 = 2 * wcol - 1;
#pragma unroll
  for (int kh = 0; kh < 3; kh++) {
    int ih = ih0 + kh;
#pragma unroll
    for (int kw = 0; kw < 3; kw++) {
      int iw = iw0 + kw;
      bool ok = (ih >= 0) && (ih < 128) && (iw >= 0) && (iw < 256);
      xv[kh][kw] = ok ? xb[ih * 256 + iw] : 0.f;
    }
  }
  __syncthreads();
  size_t base = (size_t)blk * 8192 + wcol;
  for (int c = 0; c < 64; c++) {
    const float* wc = &w[c * 9];
    float acc = 0.f;
#pragma unroll
    for (int kh = 0; kh < 3; kh++)
#pragma unroll
      for (int kw = 0; kw < 3; kw++) acc += xv[kh][kw] * wc[kh * 3 + kw];
    unsigned short hi = f2bf(acc);
    ctx_hi[base + c * 128] = hi;
    ctx_lo[base + c * 128] = f2bf(acc - bf2f(hi));
  }
}

// ---------------- K3: ctxW += context @ W_ih^T  (2-term split, split-K x4) -------
// XCD-chunked bijective block remap (768 % 8 == 0). LDS 24 KB.
__global__ __launch_bounds__(256) void k_gemm(
    const unsigned short* __restrict__ A_hi, const unsigned short* __restrict__ A_lo,
    const unsigned short* __restrict__ B_r,
    float* __restrict__ ctxW, float* __restrict__ part, int use_part) {
  __shared__ unsigned short Ah[128 * 32], Al[128 * 32], Br[128 * 32];  // 24 KB
  int tid = threadIdx.x;
  int wg = (blockIdx.x & 7) * 96 + (blockIdx.x >> 3);  // bijective
  int m0 = (wg & 15) * 128;
  int n0 = ((wg >> 4) % 12) * 128;
  int zb = wg / 192;
  size_t kb = (size_t)zb * 2048;
  int wave = tid >> 6, lane = tid & 63;
  int wm = wave >> 1, wn = wave & 1;
  const int srow = lane >> 2;
  const int sql = lane & 3;

  f32x4 acc[4][4];
  const f32x4 zero4 = {0.f, 0.f, 0.f, 0.f};
  for (int mi = 0; mi < 4; mi++)
    for (int ni = 0; ni < 4; ni++) acc[mi][ni] = zero4;

  for (int t = 0; t < 64; t++) {
    __syncthreads();
#pragma unroll
    for (int c = 0; c < 2; c++) {
      int seg = wave * 2 + c;
      int row = seg * 16 + srow;
      int scol = ((sql ^ ((row >> 1) & 3)) * 8);
      size_t ga = (size_t)(m0 + row) * 8192 + kb + t * 32 + scol;
      size_t gb = (size_t)(n0 + row) * 8192 + kb + t * 32 + scol;
      gload16(&A_hi[ga], &Ah[seg * 512]);
      gload16(&A_lo[ga], &Al[seg * 512]);
      gload16(&B_r[gb], &Br[seg * 512]);
    }
    asm volatile("s_waitcnt vmcnt(0)" ::: "memory");
    __syncthreads();
    int q = lane >> 4;
    short8 ah[4], al4[4], br8[4];
#pragma unroll
    for (int mi = 0; mi < 4; mi++) {
      int r = wm * 64 + mi * 16 + (lane & 15);
      int kc = (q ^ ((r >> 1) & 3)) * 8;
      ah[mi]  = *(short8*)&Ah[r * 32 + kc];
      al4[mi] = *(short8*)&Al[r * 32 + kc];
    }
#pragma unroll
    for (int ni = 0; ni < 4; ni++) {
      int r = wn * 64 + ni * 16 + (lane & 15);
      int kc = (q ^ ((r >> 1) & 3)) * 8;
      br8[ni] = *(short8*)&Br[r * 32 + kc];
    }
#pragma unroll
    for (int mi = 0; mi < 4; mi++)
#pragma unroll
      for (int ni = 0; ni < 4; ni++) {
        acc[mi][ni] = MFMA16(ah[mi], br8[ni], acc[mi][ni]);
        acc[mi][ni] = MFMA16(al4[mi], br8[ni], acc[mi][ni]);
      }
  }
  float* base = ctxW;
  if (use_part && zb > 0) base = part + (size_t)(zb - 1) * 3145728;
#pragma unroll
  for (int mi = 0; mi < 4; mi++)
#pragma unroll
    for (int ni = 0; ni < 4; ni++) {
      int n = n0 + wn * 64 + ni * 16 + (lane & 15);
      int mb = m0 + wm * 64 + mi * 16 + (lane >> 4) * 4;
      int bb = mb >> 6, l = mb & 63;
      size_t off = (size_t)(bb * 1536 + n) * 64 + l;
      if (use_part) {
        *(f32x4*)&base[off] = acc[mi][ni];
      } else {
#pragma unroll
        for (int r = 0; r < 4; r++) unsafeAtomicAdd(&ctxW[off + r], acc[mi][ni][r]);
      }
    }
}

// ---------------- K3r: reduce split-K partials into ctxW -------------------------
__global__ __launch_bounds__(256) void k_red(
    float* __restrict__ ctxW, const float* __restrict__ part) {
  unsigned int i4 = blockIdx.x * 256u + threadIdx.x;
  if (i4 >= 786432u) return;
  f32x4 s = *(const f32x4*)&ctxW[i4 * 4];
  s += *(const f32x4*)&part[i4 * 4];
  s += *(const f32x4*)&part[3145728 + i4 * 4];
  s += *(const f32x4*)&part[6291456 + i4 * 4];
  *(f32x4*)&ctxW[i4 * 4] = s;
}

// ---------------- K4: scan — 256 wgs (8 bg x 4 b x 32 j), R17 structure ----------
__global__ __launch_bounds__(512) void k_scan(
    const float* __restrict__ ctxW, const float* __restrict__ whh,
    const float* __restrict__ kw, const float* __restrict__ bw,
    const float* __restrict__ ow, const float* __restrict__ ob,
    unsigned int* __restrict__ hbuf, int* __restrict__ flags,
    float* __restrict__ d_out) {
  __shared__ unsigned short whh_h[48 * 512], whh_l[48 * 512];  // swizzled
  __shared__ unsigned short h_h[5 * 512], h_l[5 * 512];        // rows 0-3; row 4 = 0
  __shared__ float ws_lds[4][68];   // padded
  __shared__ float gh_lds[16][52];  // padded (rows 4-15 receive zeros)
  __shared__ int   w0_l[4];
  __shared__ float obs[17];

  const int wg = blockIdx.x;
  const int g = wg & 31, bg = wg >> 5;
  const int j0 = g * 16;
  const int tid = threadIdx.x;
  const int wave = tid >> 6, lane = tid & 63;
  float h_prev = 0.f;         // owned (b,jj) for waves 6-7 half==0
  float kappa = 0.f;          // waves 0-3: kappa for b = bg*4 + wave

  const f32x4 kwr0 = *(const f32x4*)&kw[lane * 8];
  const f32x4 kwr1 = *(const f32x4*)&kw[lane * 8 + 4];
  const f32x4 bwr0 = *(const f32x4*)&bw[lane * 8];
  const f32x4 bwr1 = *(const f32x4*)&bw[lane * 8 + 4];

  const int d_idx  = tid - 384;
  const int d_half = d_idx & 1;
  const int d_b    = (d_idx >> 1) >> 4;
  const int d_jj   = (d_idx >> 1) & 15;

  const int f_bo  = g >> 3;
  const int f_ks0 = (g & 7) * 2;
  const int f_nk  = ((g & 7) == 7) ? 3 : 2;
  const int f_t   = tid - 192;
  const bool f_act = (f_t >= 0) && (f_t < f_nk * 16);
  const int f_k  = f_ks0 + (f_t >> 4);
  const int f_ln = f_t & 15;
  const int f_sw = f_bo << 4;

  if (tid < 17) obs[tid] = ob[tid];
  *(unsigned short*)((char*)h_h + 4 * 1024 + tid * 2) = 0;
  *(unsigned short*)((char*)h_l + 4 * 1024 + tid * 2) = 0;
#pragma unroll 4
  for (int r = 0; r < 48; r++) {
    int n_g = (r >> 4) * 512 + j0 + (r & 15);
    float w = whh[n_g * 512 + tid];
    unsigned short hi = f2bf(w);
    unsigned short lo = f2bf(w - bf2f(hi));
    int byte = (r * 1024 + tid * 2) ^ ((r & 7) << 4);
    *(unsigned short*)((char*)whh_h + byte) = hi;
    *(unsigned short*)((char*)whh_l + byte) = lo;
  }
  __syncthreads();

  for (int t = 0; t < 64; t++) {
    if (tid < 32) {
      const int* fp = flags + ((t * 8 + bg) * 32 + tid) * 16;
      while (__hip_atomic_load(fp, __ATOMIC_RELAXED, __HIP_MEMORY_SCOPE_AGENT) == 0)
        __builtin_amdgcn_s_sleep(1);
    }
    __syncthreads();
    asm volatile("" ::: "memory");
    // ---- Phase A (waves 0-3): stage h row b=wave, kappa/beta (regs), weights ----
    if (wave < 4) {
      const unsigned int* src =
          hbuf + t * 16384 + (bg * 4 + wave) * 512 + lane * 8;
      u32x4 v0 = *(const u32x4*)(src);
      u32x4 v1 = *(const u32x4*)(src + 4);
      short8 hsv, lsv;
      float kd = 0.f, bd = 0.f;
#pragma unroll
      for (int e = 0; e < 8; e++) {
        unsigned int u = (e < 4) ? v0[e] : v1[e - 4];
        hsv[e] = (short)(u >> 16);
        lsv[e] = (short)(u & 0xffffu);
        float hv = __uint_as_float(u & 0xffff0000u) + __uint_as_float(u << 16);
        float kv = (e < 4) ? kwr0[e] : kwr1[e - 4];
        float bv = (e < 4) ? bwr0[e] : bwr1[e - 4];
        kd = fmaf(hv, kv, kd);
        bd = fmaf(hv, bv, bd);
      }
      int byte = (wave * 1024 + lane * 16) ^ (wave << 4);
      *(short8*)((char*)h_h + byte) = hsv;
      *(short8*)((char*)h_l + byte) = lsv;
#pragma unroll
      for (int mm = 1; mm < 64; mm <<= 1) {
        kd += __shfl_xor(kd, mm, 64);
        bd += __shfl_xor(bd, mm, 64);
      }
      kappa += kd;
      float beta = expf(bd);
      float d = kappa - (float)lane;
      float wv = expf(-beta * d * d);
      ws_lds[wave][lane] = wv;
      if (g - 8 == wave)
        d_out[34816 + (((bg * 4 + wave) << 6) + t) * 64 + lane] = wv;
      if (lane == 0) {
        int w0 = ((int)roundf(kappa) - 14) & ~3;
        w0_l[wave] = w0 < 0 ? 0 : (w0 > 32 ? 32 : w0);
      }
    }
    __syncthreads();
    // ---- Phase C (waves 0-2): gh MFMA || D (waves 6-7) || F (waves 3-4) ----
    if (wave < 3) {
      int nrow = wave * 16 + (lane & 15);
      int ar = lane & 15;
      int arow = ar < 4 ? ar : 4;
      int swb = (nrow & 7) << 4, swa = arow << 4;
      f32x4 acc = {0.f, 0.f, 0.f, 0.f};
      for (int ks = 0; ks < 16; ks++) {
        int kb2 = ks * 64 + (lane >> 4) * 16;
        short8 ah = *(short8*)((char*)h_h + ((arow * 1024 + kb2) ^ swa));
        short8 al = *(short8*)((char*)h_l + ((arow * 1024 + kb2) ^ swa));
        short8 bh = *(short8*)((char*)whh_h + ((nrow * 1024 + kb2) ^ swb));
        short8 bl = *(short8*)((char*)whh_l + ((nrow * 1024 + kb2) ^ swb));
        acc = MFMA16(ah, bh, acc);
        acc = MFMA16(ah, bl, acc);
        acc = MFMA16(al, bh, acc);
      }
#pragma unroll
      for (int r = 0; r < 4; r++)
        gh_lds[(lane >> 4) * 4 + r][wave * 16 + (lane & 15)] = acc[r];
    } else if (f_act && t > 0) {
      float s = 0.f;
#pragma unroll
      for (int c = 0; c < 4; c++) {
        int chunk = f_ln + c * 16;
        int byteoff = (f_bo * 1024 + chunk * 16) ^ f_sw;
        short8 hh8 = *(short8*)((char*)h_h + byteoff);
        short8 hl8 = *(short8*)((char*)h_l + byteoff);
        const float* owr = ow + f_k * 512 + chunk * 8;
#pragma unroll
        for (int e = 0; e < 8; e++) {
          float hv = bf2f((unsigned short)hh8[e]) + bf2f((unsigned short)hl8[e]);
          s = fmaf(hv, owr[e], s);
        }
      }
#pragma unroll
      for (int mm = 1; mm < 16; mm <<= 1) s += __shfl_xor(s, mm, 64);
      if (f_ln == 0)
        d_out[(((bg * 4 + f_bo) << 6) + (t - 1)) * 17 + f_k] = s + obs[f_k];
    }
    float gx0 = 0.f, gx1 = 0.f, gx2 = 0.f;
    if (wave >= 6) {
      int w0 = w0_l[d_b];
      const float* cb = ctxW +
          (size_t)((bg * 4 + d_b) * 1536 + j0 + d_jj) * 64 + w0 + d_half * 16;
#pragma unroll
      for (int lc = 0; lc < 4; lc++) {
        f32x4 w4 = *(const f32x4*)&ws_lds[d_b][w0 + d_half * 16 + lc * 4];
        f32x4 c0 = *(const f32x4*)(cb + lc * 4);
        f32x4 c1 = *(const f32x4*)(cb + 32768 + lc * 4);
        f32x4 c2 = *(const f32x4*)(cb + 65536 + lc * 4);
#pragma unroll
        for (int qq = 0; qq < 4; qq++) {
          gx0 = fmaf(w4[qq], c0[qq], gx0);
          gx1 = fmaf(w4[qq], c1[qq], gx1);
          gx2 = fmaf(w4[qq], c2[qq], gx2);
        }
      }
      float o0 = __shfl_xor(gx0, 1, 64);
      float o1 = __shfl_xor(gx1, 1, 64);
      float o2 = __shfl_xor(gx2, 1, 64);
      if (d_half == 0) { gx0 += o0; gx1 += o1; gx2 += o2; }
      else             { gx0 = o0 + gx0; gx1 = o1 + gx1; gx2 = o2 + gx2; }
    }
    __syncthreads();
    // ---- Phase E (waves 6-7, half==0): gates + update + publish h ----
    if (wave >= 6 && d_half == 0) {
      float rr = sigm(gx0 + gh_lds[d_b][d_jj]);
      float zz = sigm(gx1 + gh_lds[d_b][16 + d_jj]);
      float nn = tanhf(gx2 + rr * gh_lds[d_b][32 + d_jj]);
      float h = (1.f - zz) * nn + zz * h_prev;
      h_prev = h;
      unsigned short hh = f2bf(h);
      unsigned short hl = f2bf(h - bf2f(hh));
      __hip_atomic_store(&hbuf[(t + 1) * 16384 + (bg * 4 + d_b) * 512 + j0 + d_jj],
                         ((unsigned int)hh << 16) | (unsigned int)hl,
                         __ATOMIC_RELAXED, __HIP_MEMORY_SCOPE_AGENT);
    }
    __syncthreads();  // drain h stores
    if (tid == 0)
      __hip_atomic_store(&flags[(((t + 1) * 8 + bg) * 32 + g) * 16], 1,
                         __ATOMIC_RELAXED, __HIP_MEMORY_SCOPE_AGENT);
  }
  // ---- final out(63) from hbuf[64] ----
  if (tid < 32) {
    const int* fp = flags + ((64 * 8 + bg) * 32 + tid) * 16;
    while (__hip_atomic_load(fp, __ATOMIC_RELAXED, __HIP_MEMORY_SCOPE_AGENT) == 0)
      __builtin_amdgcn_s_sleep(1);
  }
  __syncthreads();
  asm volatile("" ::: "memory");
  if (f_act) {
    const unsigned int* hrow =
        hbuf + 64 * 16384 + (bg * 4 + f_bo) * 512 + f_ln * 32;
    const float* owr = ow + f_k * 512 + f_ln * 32;
    float s = 0.f;
#pragma unroll
    for (int qq = 0; qq < 8; qq++) {
      u32x4 v = *(const u32x4*)(hrow + qq * 4);
      f32x4 w4 = *(const f32x4*)(owr + qq * 4);
#pragma unroll
      for (int e = 0; e < 4; e++) {
        float hv = __uint_as_float(v[e] & 0xffff0000u) +
                   __uint_as_float(v[e] << 16);
        s = fmaf(hv, w4[e], s);
      }
    }
#pragma unroll
    for (int mm = 1; mm < 16; mm <<= 1) s += __shfl_xor(s, mm, 64);
    if (f_ln == 0)
      d_out[(((bg * 4 + f_bo) << 6) + 63) * 17 + f_k] = s + obs[f_k];
  }
}

// ---------------- launch ----------------
extern "C" void kernel_launch(void* const* d_in, const int* in_sizes, int n_in,
                              void* d_out, int out_size, void* d_ws, size_t ws_size,
                              hipStream_t stream) {
  (void)in_sizes; (void)n_in; (void)out_size;
  const float* x   = (const float*)d_in[0];
  const float* cw  = (const float*)d_in[2];
  const float* kw  = (const float*)d_in[3];
  const float* bw  = (const float*)d_in[4];
  const float* wih = (const float*)d_in[5];
  const float* whh = (const float*)d_in[6];
  const float* ow  = (const float*)d_in[7];
  const float* ob  = (const float*)d_in[8];
  float* out = (float*)d_out;
  char* ws = (char*)d_ws;

  unsigned short* ctx_hi = (unsigned short*)(ws);
  unsigned short* ctx_lo = (unsigned short*)(ws + 33554432);
  unsigned short* wih_r  = (unsigned short*)(ws + 67108864);  // 25.2 MB
  unsigned int*   hbuf   = (unsigned int*)(ws + 92274688);    // [65][16384] u32
  int*            flags  = (int*)(ws + 96993280);             // [65][8][32][16]
  float*          ctxW   = (float*)(ws + 120586240);          // [32][1536][64] f32
  float*          part   = (float*)(ws + 134217728);          // gated 3 x 12 MB
  int use_part = (ws_size >= 134217728ull + 3ull * 12582912ull) ? 1 : 0;

  k_prep<<<12288, 256, 0, stream>>>(wih, wih_r, ctxW, hbuf, flags);
  k_conv<<<2048, 128, 0, stream>>>(x, cw, ctx_hi, ctx_lo);
  k_gemm<<<768, 256, 0, stream>>>(ctx_hi, ctx_lo, wih_r, ctxW, part, use_part);
  if (use_part) k_red<<<3072, 256, 0, stream>>>(ctxW, part);
  k_scan<<<256, 512, 0, stream>>>(ctxW, whh, kw, bw, ow, ob, hbuf, flags, out);
}